// Round 8
// baseline (100.634 us; speedup 1.0000x reference)
//
#include <hip/hip_runtime.h>

#define NCLS 19
#define CM_BINS (NCLS * NCLS)   // 361
#define EPS 1e-5f
#define HW 262144               // 512*512
#define BLOCK 256
#define GRID 4096               // n_vec / BLOCK -> exactly 1 iter per thread

typedef float f32x4 __attribute__((ext_vector_type(4)));
typedef int   i32x4 __attribute__((ext_vector_type(4)));

__global__ void __launch_bounds__(BLOCK)
dice_cm_kernel(const float* __restrict__ y_pred,
               const int* __restrict__ y,
               unsigned int* __restrict__ cm,
               int n_vec) {
    __shared__ unsigned int s_cm[CM_BINS];
    const int tid = threadIdx.x;
    for (int i = tid; i < CM_BINS; i += BLOCK) s_cm[i] = 0u;
    __syncthreads();

    // One pixel-quad per thread (GRID*BLOCK == n_vec): no grid-stride second
    // iteration -> no intra-thread serialization between load bursts (R7
    // lesson: the 2-iter loop stalled each wave twice; block scheduling
    // pipelines single-burst blocks for free).
    // Fixed ascending plane order, strict > = jnp.argmax first-occurrence
    // (R7 lesson: runtime-rotated order serialized address calc, -24%).
    for (int pv = blockIdx.x * BLOCK + tid; pv < n_vec; pv += GRID * BLOCK) {
        const int b   = pv >> 16;        // pv / (HW/4)
        const int hw4 = pv & 65535;      // pv % (HW/4)
        const float* p = y_pred + (size_t)b * ((size_t)NCLS * HW) + (size_t)hw4 * 4;

        f32x4 best = __builtin_nontemporal_load(reinterpret_cast<const f32x4*>(p));
        int bcx = 0, bcy = 0, bcz = 0, bcw = 0;
        #pragma unroll
        for (int c = 1; c < NCLS; ++c) {
            const f32x4 v = __builtin_nontemporal_load(
                reinterpret_cast<const f32x4*>(p + (size_t)c * HW));
            if (v.x > best.x) { best.x = v.x; bcx = c; }
            if (v.y > best.y) { best.y = v.y; bcy = c; }
            if (v.z > best.z) { best.z = v.z; bcz = c; }
            if (v.w > best.w) { best.w = v.w; bcw = c; }
        }

        const i32x4 lab = __builtin_nontemporal_load(
            reinterpret_cast<const i32x4*>(y) + pv);

        atomicAdd(&s_cm[lab.x * NCLS + bcx], 1u);
        atomicAdd(&s_cm[lab.y * NCLS + bcy], 1u);
        atomicAdd(&s_cm[lab.z * NCLS + bcz], 1u);
        atomicAdd(&s_cm[lab.w * NCLS + bcw], 1u);
    }

    __syncthreads();
    for (int i = tid; i < CM_BINS; i += BLOCK) {
        const unsigned int v = s_cm[i];
        if (v) atomicAdd(&cm[i], v);
    }
}

__global__ void dice_finalize(const unsigned int* __restrict__ cm,
                              float* __restrict__ out) {
    const int lane = threadIdx.x;
    float d = 0.0f;
    if (lane < NCLS) {
        float cy = 0.0f, cp = 0.0f;
        #pragma unroll
        for (int j = 0; j < NCLS; ++j) {
            cy += (float)cm[lane * NCLS + j];   // row sum: |y==lane|
            cp += (float)cm[j * NCLS + lane];   // col sum: |pred==lane|
        }
        const float inter = (float)cm[lane * NCLS + lane];
        const float uni   = cy + cp - inter;
        d = (2.0f * inter + EPS) / (uni + EPS);
    }
    #pragma unroll
    for (int off = 32; off > 0; off >>= 1) d += __shfl_down(d, off);
    if (lane == 0) out[0] = 1.0f - d * (1.0f / (float)NCLS);
}

extern "C" void kernel_launch(void* const* d_in, const int* in_sizes, int n_in,
                              void* d_out, int out_size, void* d_ws, size_t ws_size,
                              hipStream_t stream) {
    const float* y_pred = (const float*)d_in[0];
    const int*   y      = (const int*)d_in[1];
    float*       out    = (float*)d_out;
    unsigned int* cm    = (unsigned int*)d_ws;

    // zero the 361-bin confusion matrix (harness poisons d_ws with 0xAA)
    hipMemsetAsync(cm, 0, CM_BINS * sizeof(unsigned int), stream);

    const int n_pix = in_sizes[1];     // 16*512*512
    const int n_vec = n_pix / 4;       // 1,048,576 = GRID*BLOCK exactly

    dice_cm_kernel<<<GRID, BLOCK, 0, stream>>>(y_pred, y, cm, n_vec);
    dice_finalize<<<1, 64, 0, stream>>>(cm, out);
}

// Round 9
// 66.914 us; speedup vs baseline: 1.5039x; 1.5039x over previous
//
#include <hip/hip_runtime.h>

#define NCLS 19
#define CM_BINS (NCLS * NCLS)   // 361
#define EPS 1e-5f
#define HW 262144               // 512*512
#define BLOCK 256
#define GRID 1024               // 4 grid-stride iters/thread (scan: 4096=100.6, 2048=76.7, 1024=?)

typedef float f32x4 __attribute__((ext_vector_type(4)));
typedef int   i32x4 __attribute__((ext_vector_type(4)));

__global__ void __launch_bounds__(BLOCK)
dice_cm_kernel(const float* __restrict__ y_pred,
               const int* __restrict__ y,
               unsigned int* __restrict__ cm,
               int n_vec) {
    __shared__ unsigned int s_cm[CM_BINS];
    const int tid = threadIdx.x;
    for (int i = tid; i < CM_BINS; i += BLOCK) s_cm[i] = 0u;
    __syncthreads();

    // Fixed ascending plane order, strict > = jnp.argmax first-occurrence
    // (R7: runtime-rotated order serialized address calc, -24%).
    // 4 iters/thread: fewer blocks -> less per-block overhead + half the
    // global flush atomics vs 2048 blocks (R8: 1 iter/thread regressed 31%).
    for (int pv = blockIdx.x * BLOCK + tid; pv < n_vec; pv += GRID * BLOCK) {
        const int b   = pv >> 16;        // pv / (HW/4)
        const int hw4 = pv & 65535;      // pv % (HW/4)
        const float* p = y_pred + (size_t)b * ((size_t)NCLS * HW) + (size_t)hw4 * 4;

        f32x4 best = __builtin_nontemporal_load(reinterpret_cast<const f32x4*>(p));
        int bcx = 0, bcy = 0, bcz = 0, bcw = 0;
        #pragma unroll
        for (int c = 1; c < NCLS; ++c) {
            const f32x4 v = __builtin_nontemporal_load(
                reinterpret_cast<const f32x4*>(p + (size_t)c * HW));
            if (v.x > best.x) { best.x = v.x; bcx = c; }
            if (v.y > best.y) { best.y = v.y; bcy = c; }
            if (v.z > best.z) { best.z = v.z; bcz = c; }
            if (v.w > best.w) { best.w = v.w; bcw = c; }
        }

        const i32x4 lab = __builtin_nontemporal_load(
            reinterpret_cast<const i32x4*>(y) + pv);

        atomicAdd(&s_cm[lab.x * NCLS + bcx], 1u);
        atomicAdd(&s_cm[lab.y * NCLS + bcy], 1u);
        atomicAdd(&s_cm[lab.z * NCLS + bcz], 1u);
        atomicAdd(&s_cm[lab.w * NCLS + bcw], 1u);
    }

    __syncthreads();
    for (int i = tid; i < CM_BINS; i += BLOCK) {
        const unsigned int v = s_cm[i];
        if (v) atomicAdd(&cm[i], v);
    }
}

__global__ void dice_finalize(const unsigned int* __restrict__ cm,
                              float* __restrict__ out) {
    const int lane = threadIdx.x;
    float d = 0.0f;
    if (lane < NCLS) {
        float cy = 0.0f, cp = 0.0f;
        #pragma unroll
        for (int j = 0; j < NCLS; ++j) {
            cy += (float)cm[lane * NCLS + j];   // row sum: |y==lane|
            cp += (float)cm[j * NCLS + lane];   // col sum: |pred==lane|
        }
        const float inter = (float)cm[lane * NCLS + lane];
        const float uni   = cy + cp - inter;
        d = (2.0f * inter + EPS) / (uni + EPS);
    }
    #pragma unroll
    for (int off = 32; off > 0; off >>= 1) d += __shfl_down(d, off);
    if (lane == 0) out[0] = 1.0f - d * (1.0f / (float)NCLS);
}

extern "C" void kernel_launch(void* const* d_in, const int* in_sizes, int n_in,
                              void* d_out, int out_size, void* d_ws, size_t ws_size,
                              hipStream_t stream) {
    const float* y_pred = (const float*)d_in[0];
    const int*   y      = (const int*)d_in[1];
    float*       out    = (float*)d_out;
    unsigned int* cm    = (unsigned int*)d_ws;

    // zero the 361-bin confusion matrix (harness poisons d_ws with 0xAA)
    hipMemsetAsync(cm, 0, CM_BINS * sizeof(unsigned int), stream);

    const int n_pix = in_sizes[1];     // 16*512*512
    const int n_vec = n_pix / 4;       // 1,048,576 -> exactly 4 iters/thread

    dice_cm_kernel<<<GRID, BLOCK, 0, stream>>>(y_pred, y, cm, n_vec);
    dice_finalize<<<1, 64, 0, stream>>>(cm, out);
}

// Round 11
// 63.252 us; speedup vs baseline: 1.5910x; 1.0579x over previous
//
#include <hip/hip_runtime.h>

#define NCLS 19
#define CM_BINS (NCLS * NCLS)   // 361
#define EPS 1e-5f
#define HW 262144               // 512*512
#define BLOCK 256
#define GRID 512                // 8 iters/thread (scan: 4096=100.6, 2048=76.7, 1024=66.9, 512=?)

typedef float f32x4 __attribute__((ext_vector_type(4)));
typedef int   i32x4 __attribute__((ext_vector_type(4)));

__global__ void __launch_bounds__(BLOCK)
dice_cm_kernel(const float* __restrict__ y_pred,
               const int* __restrict__ y,
               unsigned int* __restrict__ cm,
               int n_vec) {
    __shared__ unsigned int s_cm[CM_BINS];
    const int tid = threadIdx.x;
    for (int i = tid; i < CM_BINS; i += BLOCK) s_cm[i] = 0u;
    __syncthreads();

    // Fixed ascending plane order, strict > = jnp.argmax first-occurrence
    // (R7: runtime-rotated order serialized address calc, -24%).
    // Fewer blocks -> amortized per-block cost (LDS zero + 361-bin global
    // flush). Scan: 4096=100.6, 2048=76.7, 1024=66.9 -> try 512.
    for (int pv = blockIdx.x * BLOCK + tid; pv < n_vec; pv += GRID * BLOCK) {
        const int b   = pv >> 16;        // pv / (HW/4)
        const int hw4 = pv & 65535;      // pv % (HW/4)
        const float* p = y_pred + (size_t)b * ((size_t)NCLS * HW) + (size_t)hw4 * 4;

        f32x4 best = __builtin_nontemporal_load(reinterpret_cast<const f32x4*>(p));
        int bcx = 0, bcy = 0, bcz = 0, bcw = 0;
        #pragma unroll
        for (int c = 1; c < NCLS; ++c) {
            const f32x4 v = __builtin_nontemporal_load(
                reinterpret_cast<const f32x4*>(p + (size_t)c * HW));
            if (v.x > best.x) { best.x = v.x; bcx = c; }
            if (v.y > best.y) { best.y = v.y; bcy = c; }
            if (v.z > best.z) { best.z = v.z; bcz = c; }
            if (v.w > best.w) { best.w = v.w; bcw = c; }
        }

        const i32x4 lab = __builtin_nontemporal_load(
            reinterpret_cast<const i32x4*>(y) + pv);

        atomicAdd(&s_cm[lab.x * NCLS + bcx], 1u);
        atomicAdd(&s_cm[lab.y * NCLS + bcy], 1u);
        atomicAdd(&s_cm[lab.z * NCLS + bcz], 1u);
        atomicAdd(&s_cm[lab.w * NCLS + bcw], 1u);
    }

    __syncthreads();
    for (int i = tid; i < CM_BINS; i += BLOCK) {
        const unsigned int v = s_cm[i];
        if (v) atomicAdd(&cm[i], v);
    }
}

__global__ void dice_finalize(const unsigned int* __restrict__ cm,
                              float* __restrict__ out) {
    const int lane = threadIdx.x;
    float d = 0.0f;
    if (lane < NCLS) {
        float cy = 0.0f, cp = 0.0f;
        #pragma unroll
        for (int j = 0; j < NCLS; ++j) {
            cy += (float)cm[lane * NCLS + j];   // row sum: |y==lane|
            cp += (float)cm[j * NCLS + lane];   // col sum: |pred==lane|
        }
        const float inter = (float)cm[lane * NCLS + lane];
        const float uni   = cy + cp - inter;
        d = (2.0f * inter + EPS) / (uni + EPS);
    }
    #pragma unroll
    for (int off = 32; off > 0; off >>= 1) d += __shfl_down(d, off);
    if (lane == 0) out[0] = 1.0f - d * (1.0f / (float)NCLS);
}

extern "C" void kernel_launch(void* const* d_in, const int* in_sizes, int n_in,
                              void* d_out, int out_size, void* d_ws, size_t ws_size,
                              hipStream_t stream) {
    const float* y_pred = (const float*)d_in[0];
    const int*   y      = (const int*)d_in[1];
    float*       out    = (float*)d_out;
    unsigned int* cm    = (unsigned int*)d_ws;

    // zero the 361-bin confusion matrix (harness poisons d_ws with 0xAA)
    hipMemsetAsync(cm, 0, CM_BINS * sizeof(unsigned int), stream);

    const int n_pix = in_sizes[1];     // 16*512*512
    const int n_vec = n_pix / 4;       // 1,048,576 -> exactly 8 iters/thread

    dice_cm_kernel<<<GRID, BLOCK, 0, stream>>>(y_pred, y, cm, n_vec);
    dice_finalize<<<1, 64, 0, stream>>>(cm, out);
}